// Round 8
// baseline (567.612 us; speedup 1.0000x reference)
//
#include <hip/hip_runtime.h>
#include <hip/hip_bf16.h>

#define DIMD 256
#define DIMC 64
#define RPT  16   // rows per tile
#define OTS  68   // out-bounce row stride (floats)

typedef __attribute__((ext_vector_type(8))) __bf16 bf16x8;
typedef __attribute__((ext_vector_type(4))) __bf16 bf16x4;
typedef __attribute__((ext_vector_type(4))) float f32x4;
typedef __attribute__((ext_vector_type(4))) int i32x4;

__global__ __launch_bounds__(256, 4) void tree_node_kernel(
    const float* __restrict__ x,
    const float* __restrict__ w_router,
    const float* __restrict__ b_router,
    const float* __restrict__ w_left,
    const float* __restrict__ b_left,
    const float* __restrict__ w_right,
    const float* __restrict__ b_right,
    float* __restrict__ out,
    int iters)
{
    __shared__ __bf16 xb16[2][RPT * DIMD];                  // 2 x 8 KB, swizzled
    __shared__ float  obuf[2][RPT * OTS];                   // 8.5 KB bounce
    __shared__ float  wr_s[DIMD];                           // 1 KB router w
    __shared__ int    mask_lds[2][RPT] __attribute__((aligned(16)));

    const int tid  = threadIdx.x;
    const int lane = tid & 63;
    const int wave = tid >> 6;
    const int g    = lane >> 4;   // k-group 0..3 (MFMA)
    const int m    = lane & 15;   // row (A) / col (B) within 16-tile
    const int srow = tid >> 4;    // staging row 0..15
    const int sm   = tid & 15;    // staging chunk 0..15

    // ---- prologue: B weights -> registers (wave w owns cols [16w,16w+16)) ----
    const int col = wave * 16 + m;
    bf16x8 bL[8], bR[8];
#pragma unroll
    for (int s = 0; s < 8; ++s)
#pragma unroll
        for (int j = 0; j < 8; ++j) {
            const int k = s * 32 + g * 8 + j;
            bL[s][j] = (__bf16)w_left[k * DIMC + col];
            bR[s][j] = (__bf16)w_right[k * DIMC + col];
        }
    const float biasL = b_left[col];
    const float biasR = b_right[col];
    const float brout = b_router[0];
    wr_s[tid] = w_router[tid];

    // GRID-STRIDED tile mapping (dense moving front)
    const size_t row_base   = (size_t)blockIdx.x * RPT;
    const size_t row_stride = (size_t)gridDim.x * RPT;
#define ROW0(itile) (row_base + (size_t)(itile) * row_stride)

    __syncthreads();   // wr_s ready

    // TWO staging register sets: tile t lives in set t&1. Keeps >=1 tile of
    // reads in flight per block at ALL times (Little's law: need ~30KB/CU,
    // single-set schedule averaged only ~17KB/CU -> 70% of BW ceiling).
    f32x4 sxA[4], sxB[4];

#define ISSUE(itile, SET)                                                     \
    {                                                                         \
        const float* xr = x + (ROW0(itile) + srow) * DIMD + sm * 4;           \
        _Pragma("unroll")                                                     \
        for (int j = 0; j < 4; ++j) SET[j] = *(const f32x4*)(xr + j * 64);    \
    }

    // consume: fp64 router partial + cvt bf16 + swizzled LDS write + mask.
    // swizzle: 16B piece p -> p ^ (row&7); same involution on A-frag reads.
#define CONSUME(itile, SET)                                                   \
    {                                                                         \
        const int slot = (itile) & 1;                                         \
        double racc = 0.0;                                                    \
        const int rx = srow & 7;                                              \
        _Pragma("unroll")                                                     \
        for (int j = 0; j < 4; ++j) {                                         \
            const f32x4 wv = *(const f32x4*)&wr_s[sm * 4 + j * 64];           \
            bf16x4 v;                                                         \
            _Pragma("unroll")                                                 \
            for (int e = 0; e < 4; ++e) {                                     \
                racc += (double)SET[j][e] * (double)wv[e];                    \
                v[e] = (__bf16)SET[j][e];                                     \
            }                                                                 \
            const int p = (sm >> 1) + 8 * j;                                  \
            *(bf16x4*)&xb16[slot][srow * DIMD +                               \
                (((p ^ rx) << 3) | ((sm & 1) << 2))] = v;                     \
        }                                                                     \
        racc += __shfl_xor(racc, 1);                                          \
        racc += __shfl_xor(racc, 2);                                          \
        racc += __shfl_xor(racc, 4);                                          \
        racc += __shfl_xor(racc, 8);                                          \
        if (sm == 0)                                                          \
            mask_lds[slot][srow] =                                            \
                ((float)(racc + (double)brout) > 0.0f) ? 1 : 0;               \
    }

    // one pipeline step for tile t; consumes t+1 / issues t+3 in set (t+1)&1
#define STEP(t, SET)                                                          \
    {                                                                         \
        if ((t) > 0) {                                                        \
            const f32x4 ov = *(const f32x4*)                                  \
                &obuf[((t) - 1) & 1][(tid >> 4) * OTS + (tid & 15) * 4];      \
            *(f32x4*)(out + ROW0((t) - 1) * DIMC + (size_t)tid * 4) = ov;     \
        }                                                                     \
        const __bf16* xb = &xb16[(t) & 1][0];                                 \
        f32x4 accL = {0.f,0.f,0.f,0.f}, accR = {0.f,0.f,0.f,0.f};             \
        const int axr = m & 7;                                                \
        _Pragma("unroll")                                                     \
        for (int s = 0; s < 8; ++s) {                                         \
            const int p = s * 4 + g;                                          \
            const bf16x8 a = *(const bf16x8*)&xb[m * DIMD + ((p ^ axr) << 3)];\
            accL = __builtin_amdgcn_mfma_f32_16x16x32_bf16(a, bL[s], accL, 0, 0, 0); \
            accR = __builtin_amdgcn_mfma_f32_16x16x32_bf16(a, bR[s], accR, 0, 0, 0); \
        }                                                                     \
        if ((t) + 1 < iters) CONSUME((t) + 1, SET);   /* counted vmcnt: */    \
        if ((t) + 3 < iters) ISSUE((t) + 3, SET);     /* t+2 stays in flight*/\
        const i32x4 mk = *(const i32x4*)&mask_lds[(t) & 1][g * 4];            \
        _Pragma("unroll")                                                     \
        for (int r = 0; r < 4; ++r) {                                         \
            const float v = mk[r] ? (accL[r] + biasL) : (accR[r] + biasR);    \
            obuf[(t) & 1][(g * 4 + r) * OTS + col] = v;                       \
        }                                                                     \
        asm volatile("s_waitcnt lgkmcnt(0)" ::: "memory");                    \
        __builtin_amdgcn_s_barrier();                                         \
    }

    // ---- prologue staging: tiles 0,1,2 issued; 0 consumed; 1,2 IN FLIGHT ----
    ISSUE(0, sxA);
    ISSUE(1, sxB);
    CONSUME(0, sxA);          // waits only its own loads; loads(1) in flight
    ISSUE(2, sxA);
    asm volatile("s_waitcnt lgkmcnt(0)" ::: "memory");
    __builtin_amdgcn_s_barrier();

    // parity-unrolled main loop: tile t's consume/issue set is (t+1)&1
    for (int it = 0; it < iters; it += 2) {
        STEP(it,     sxB);    // even t: consume t+1 (odd)  -> set B
        STEP(it + 1, sxA);    // odd  t: consume t+2 (even) -> set A
    }

    // ---- drain: store last tile ----
    {
        const int it = iters - 1;
        const f32x4 ov = *(const f32x4*)
            &obuf[it & 1][(tid >> 4) * OTS + (tid & 15) * 4];
        *(f32x4*)(out + ROW0(it) * DIMC + (size_t)tid * 4) = ov;
    }
#undef ISSUE
#undef CONSUME
#undef STEP
#undef ROW0
}

extern "C" void kernel_launch(void* const* d_in, const int* in_sizes, int n_in,
                              void* d_out, int out_size, void* d_ws, size_t ws_size,
                              hipStream_t stream) {
    const float* x        = (const float*)d_in[0];
    const float* w_router = (const float*)d_in[1];
    const float* b_router = (const float*)d_in[2];
    const float* w_left   = (const float*)d_in[3];
    const float* b_left   = (const float*)d_in[4];
    const float* w_right  = (const float*)d_in[5];
    const float* b_right  = (const float*)d_in[6];
    float* out = (float*)d_out;

    const int n_tok = in_sizes[0] / DIMD;   // 1,048,576
    const int grid  = 1024;                 // 4 blocks/CU x 256 CU (LDS ~26 KB)
    const int iters = n_tok / (grid * RPT); // 64 (even -> parity loop exact)

    tree_node_kernel<<<grid, 256, 0, stream>>>(
        x, w_router, b_router, w_left, b_left, w_right, b_right, out, iters);
}

// Round 9
// 287.319 us; speedup vs baseline: 1.9755x; 1.9755x over previous
//
#include <hip/hip_runtime.h>
#include <hip/hip_bf16.h>

#define DIMD 256
#define DIMC 64
#define RPT  16   // rows per tile
#define OTS  68   // out-bounce row stride (floats)

typedef __attribute__((ext_vector_type(8))) __bf16 bf16x8;
typedef __attribute__((ext_vector_type(4))) __bf16 bf16x4;
typedef __attribute__((ext_vector_type(4))) float f32x4;
typedef __attribute__((ext_vector_type(4))) int i32x4;

__global__ __launch_bounds__(256, 4) void tree_node_kernel(
    const float* __restrict__ x,
    const float* __restrict__ w_router,
    const float* __restrict__ b_router,
    const float* __restrict__ w_left,
    const float* __restrict__ b_left,
    const float* __restrict__ w_right,
    const float* __restrict__ b_right,
    float* __restrict__ out,
    int iters)
{
    __shared__ __bf16 xb16[2][RPT * DIMD];                  // 2 x 8 KB, swizzled
    __shared__ float  obuf[2][RPT * OTS];                   // 8.5 KB bounce
    __shared__ float  wr_s[DIMD];                           // 1 KB router w
    __shared__ int    mask_lds[2][RPT] __attribute__((aligned(16)));

    const int tid  = threadIdx.x;
    const int lane = tid & 63;
    const int wave = tid >> 6;
    const int g    = lane >> 4;   // k-group 0..3 (MFMA)
    const int m    = lane & 15;   // row (A) / col (B) within 16-tile
    const int srow = tid >> 4;    // staging row 0..15
    const int sm   = tid & 15;    // staging chunk 0..15

    // ---- prologue: B weights -> registers (wave w owns cols [16w,16w+16)) ----
    const int col = wave * 16 + m;
    bf16x8 bL[8], bR[8];
#pragma unroll
    for (int s = 0; s < 8; ++s)
#pragma unroll
        for (int j = 0; j < 8; ++j) {
            const int k = s * 32 + g * 8 + j;
            bL[s][j] = (__bf16)w_left[k * DIMC + col];
            bR[s][j] = (__bf16)w_right[k * DIMC + col];
        }
    const float biasL = b_left[col];
    const float biasR = b_right[col];
    const float brout = b_router[0];
    wr_s[tid] = w_router[tid];

    // GRID-STRIDED tile mapping (dense moving front)
    const size_t row_base   = (size_t)blockIdx.x * RPT;
    const size_t row_stride = (size_t)gridDim.x * RPT;
#define ROW0(itile) (row_base + (size_t)(itile) * row_stride)

    __syncthreads();   // wr_s ready

    // ONE logical staging set, split in two 8-reg halves (j=0,1 | j=2,3).
    // Same 16 VGPR total as v7 -- no spill risk -- but two separate wait
    // points of 8 KB each, with MFMA work sandwiched between them.
    f32x4 sxH0[2], sxH1[2];

#define ISSUE_H(itile, SET, J0)                                               \
    {                                                                         \
        const float* xr = x + (ROW0(itile) + srow) * DIMD + sm * 4;           \
        SET[0] = *(const f32x4*)(xr + (J0) * 64);                             \
        SET[1] = *(const f32x4*)(xr + (J0 + 1) * 64);                         \
    }

    // consume half: fp64 router partial (same j-ascending order as v7 ->
    // bit-identical sum) + cvt bf16 + swizzled LDS write.
    // swizzle: 16B piece p -> p ^ (row&7); same involution on A-frag reads.
#define CONSUME_H(itile, SET, J0)                                             \
    {                                                                         \
        const int slot = (itile) & 1;                                         \
        const int rx = srow & 7;                                              \
        _Pragma("unroll")                                                     \
        for (int j = 0; j < 2; ++j) {                                         \
            const f32x4 wv = *(const f32x4*)&wr_s[sm * 4 + ((J0) + j) * 64];  \
            bf16x4 v;                                                         \
            _Pragma("unroll")                                                 \
            for (int e = 0; e < 4; ++e) {                                     \
                racc += (double)SET[j][e] * (double)wv[e];                    \
                v[e] = (__bf16)SET[j][e];                                     \
            }                                                                 \
            const int p = (sm >> 1) + 8 * ((J0) + j);                         \
            *(bf16x4*)&xb16[slot][srow * DIMD +                               \
                (((p ^ rx) << 3) | ((sm & 1) << 2))] = v;                     \
        }                                                                     \
    }

#define FINISH_ROUTER(itile)                                                  \
    {                                                                         \
        racc += __shfl_xor(racc, 1);                                          \
        racc += __shfl_xor(racc, 2);                                          \
        racc += __shfl_xor(racc, 4);                                          \
        racc += __shfl_xor(racc, 8);                                          \
        if (sm == 0)                                                          \
            mask_lds[(itile) & 1][srow] =                                     \
                ((float)(racc + (double)brout) > 0.0f) ? 1 : 0;               \
    }

    // 4 MFMA K-steps [S0,S0+4) on both children
#define MFMA_HALF(xb, S0)                                                     \
    _Pragma("unroll")                                                         \
    for (int s = (S0); s < (S0) + 4; ++s) {                                   \
        const int p = s * 4 + g;                                              \
        const bf16x8 a = *(const bf16x8*)&xb[m * DIMD + ((p ^ axr) << 3)];    \
        accL = __builtin_amdgcn_mfma_f32_16x16x32_bf16(a, bL[s], accL, 0, 0, 0); \
        accR = __builtin_amdgcn_mfma_f32_16x16x32_bf16(a, bR[s], accR, 0, 0, 0); \
    }

    // ---- prologue staging: tile 0 staged; tile 1 loads IN FLIGHT ----
    {
        double racc = 0.0;
        ISSUE_H(0, sxH0, 0);
        ISSUE_H(0, sxH1, 2);
        CONSUME_H(0, sxH0, 0);
        CONSUME_H(0, sxH1, 2);
        FINISH_ROUTER(0);
        ISSUE_H(1, sxH0, 0);
        ISSUE_H(1, sxH1, 2);
    }
    asm volatile("s_waitcnt lgkmcnt(0)" ::: "memory");
    __builtin_amdgcn_s_barrier();

    for (int it = 0; it < iters; ++it) {
        // ---- 1) store tile it-1 (4KB contiguous; ack never waited on) ----
        if (it > 0) {
            const f32x4 ov = *(const f32x4*)
                &obuf[(it - 1) & 1][(tid >> 4) * OTS + (tid & 15) * 4];
            *(f32x4*)(out + ROW0(it - 1) * DIMC + (size_t)tid * 4) = ov;
        }

        const __bf16* xb = &xb16[it & 1][0];
        f32x4 accL = {0.f,0.f,0.f,0.f}, accR = {0.f,0.f,0.f,0.f};
        const int axr = m & 7;
        double racc = 0.0;

        // ---- 2) MFMA s0..3 (covers delivery tail of H0(it+1)) ----
        MFMA_HALF(xb, 0);

        // ---- 3) consume H0(it+1): waits only its 8 loads (counted vmcnt);
        //         H1(it+1) loads + store stay in flight ----
        if (it + 1 < iters) CONSUME_H(it + 1, sxH0, 0);
        // ---- 4) issue H0(it+2) immediately (read stream restarts early) ----
        if (it + 2 < iters) ISSUE_H(it + 2, sxH0, 0);

        // ---- 5) MFMA s4..7 (covers delivery tail of H1(it+1)) ----
        MFMA_HALF(xb, 4);

        // ---- 6) consume H1(it+1) + finish router ----
        if (it + 1 < iters) { CONSUME_H(it + 1, sxH1, 2); FINISH_ROUTER(it + 1); }
        // ---- 7) issue H1(it+2) ----
        if (it + 2 < iters) ISSUE_H(it + 2, sxH1, 2);

        // ---- 8) epilogue tile it: select child per row -> obuf[it&1] ----
        const i32x4 mk = *(const i32x4*)&mask_lds[it & 1][g * 4];
#pragma unroll
        for (int r = 0; r < 4; ++r) {
            const float v = mk[r] ? (accL[r] + biasL) : (accR[r] + biasR);
            obuf[it & 1][(g * 4 + r) * OTS + col] = v;   // C/D: row=(lane>>4)*4+reg
        }

        // ---- 9) barrier: lgkm-only; loads(it+2) + store(it-1) in flight ----
        asm volatile("s_waitcnt lgkmcnt(0)" ::: "memory");
        __builtin_amdgcn_s_barrier();
    }

    // ---- drain: store last tile ----
    {
        const int it = iters - 1;
        const f32x4 ov = *(const f32x4*)
            &obuf[it & 1][(tid >> 4) * OTS + (tid & 15) * 4];
        *(f32x4*)(out + ROW0(it) * DIMC + (size_t)tid * 4) = ov;
    }
#undef ISSUE_H
#undef CONSUME_H
#undef FINISH_ROUTER
#undef MFMA_HALF
#undef ROW0
}

extern "C" void kernel_launch(void* const* d_in, const int* in_sizes, int n_in,
                              void* d_out, int out_size, void* d_ws, size_t ws_size,
                              hipStream_t stream) {
    const float* x        = (const float*)d_in[0];
    const float* w_router = (const float*)d_in[1];
    const float* b_router = (const float*)d_in[2];
    const float* w_left   = (const float*)d_in[3];
    const float* b_left   = (const float*)d_in[4];
    const float* w_right  = (const float*)d_in[5];
    const float* b_right  = (const float*)d_in[6];
    float* out = (float*)d_out;

    const int n_tok = in_sizes[0] / DIMD;   // 1,048,576
    const int grid  = 1024;                 // 4 blocks/CU x 256 CU (LDS ~26 KB)
    const int iters = n_tok / (grid * RPT); // 64

    tree_node_kernel<<<grid, 256, 0, stream>>>(
        x, w_router, b_router, w_left, b_left, w_right, b_right, out, iters);
}

// Round 10
// 287.178 us; speedup vs baseline: 1.9765x; 1.0005x over previous
//
#include <hip/hip_runtime.h>
#include <hip/hip_bf16.h>

#define DIMD 256
#define DIMC 64
#define RPT  16   // rows per tile
#define OTS  68   // out-bounce row stride (floats)

typedef __attribute__((ext_vector_type(8))) __bf16 bf16x8;
typedef __attribute__((ext_vector_type(4))) __bf16 bf16x4;
typedef __attribute__((ext_vector_type(4))) float f32x4;
typedef __attribute__((ext_vector_type(4))) int i32x4;

__global__ __launch_bounds__(256, 4) void tree_node_kernel(
    const float* __restrict__ x,
    const float* __restrict__ w_router,
    const float* __restrict__ b_router,
    const float* __restrict__ w_left,
    const float* __restrict__ b_left,
    const float* __restrict__ w_right,
    const float* __restrict__ b_right,
    float* __restrict__ out,
    int iters)
{
    __shared__ __bf16 xb16[2][RPT * DIMD];                  // 2 x 8 KB, swizzled
    __shared__ float  obuf[2][RPT * OTS];                   // 8.5 KB bounce
    __shared__ float  wr_s[DIMD];                           // 1 KB router w
    __shared__ int    mask_lds[2][RPT] __attribute__((aligned(16)));

    const int tid  = threadIdx.x;
    const int lane = tid & 63;
    const int wave = tid >> 6;
    const int g    = lane >> 4;   // k-group 0..3 (MFMA)
    const int m    = lane & 15;   // row (A) / col (B) within 16-tile
    const int srow = tid >> 4;    // staging row 0..15
    const int sm   = tid & 15;    // staging chunk 0..15

    // ---- PHASE STAGGER: quarter-iteration offsets so blocks' memory phases
    //      interleave chip-wide instead of bursting in lockstep. (b>>8) term
    //      decorrelates co-resident blocks {b, b+256, ...}; identical per-iter
    //      work preserves the offset. Work/results unchanged. ----
    {
        const int ph = (blockIdx.x + (blockIdx.x >> 8)) & 3;
        for (int i = 0; i < ph; ++i) __builtin_amdgcn_s_sleep(42); // ~1.1us each
    }

    // ---- prologue: B weights -> registers (wave w owns cols [16w,16w+16)) ----
    const int col = wave * 16 + m;
    bf16x8 bL[8], bR[8];
#pragma unroll
    for (int s = 0; s < 8; ++s)
#pragma unroll
        for (int j = 0; j < 8; ++j) {
            const int k = s * 32 + g * 8 + j;
            bL[s][j] = (__bf16)w_left[k * DIMC + col];
            bR[s][j] = (__bf16)w_right[k * DIMC + col];
        }
    const float biasL = b_left[col];
    const float biasR = b_right[col];
    const float brout = b_router[0];
    wr_s[tid] = w_router[tid];

    // GRID-STRIDED tile mapping (dense moving front)
    const size_t row_base   = (size_t)blockIdx.x * RPT;
    const size_t row_stride = (size_t)gridDim.x * RPT;
#define ROW0(itile) (row_base + (size_t)(itile) * row_stride)

    __syncthreads();   // wr_s ready

    f32x4 sx[4];       // staged f32 (one 16-float slice of one row)

#define ISSUE(itile)                                                          \
    {                                                                         \
        const float* xr = x + (ROW0(itile) + srow) * DIMD + sm * 4;           \
        _Pragma("unroll")                                                     \
        for (int j = 0; j < 4; ++j) sx[j] = *(const f32x4*)(xr + j * 64);     \
    }

    // consume: fp64 router partial + cvt bf16 + swizzled LDS write + mask.
    // swizzle: 16B piece p -> p ^ (row&7); same involution on A-frag reads.
#define CONSUME(itile)                                                        \
    {                                                                         \
        const int slot = (itile) & 1;                                         \
        double racc = 0.0;                                                    \
        const int rx = srow & 7;                                              \
        _Pragma("unroll")                                                     \
        for (int j = 0; j < 4; ++j) {                                         \
            const f32x4 wv = *(const f32x4*)&wr_s[sm * 4 + j * 64];           \
            bf16x4 v;                                                         \
            _Pragma("unroll")                                                 \
            for (int e = 0; e < 4; ++e) {                                     \
                racc += (double)sx[j][e] * (double)wv[e];                     \
                v[e] = (__bf16)sx[j][e];                                      \
            }                                                                 \
            const int p = (sm >> 1) + 8 * j;                                  \
            *(bf16x4*)&xb16[slot][srow * DIMD +                               \
                (((p ^ rx) << 3) | ((sm & 1) << 2))] = v;                     \
        }                                                                     \
        racc += __shfl_xor(racc, 1);                                          \
        racc += __shfl_xor(racc, 2);                                          \
        racc += __shfl_xor(racc, 4);                                          \
        racc += __shfl_xor(racc, 8);                                          \
        if (sm == 0)                                                          \
            mask_lds[slot][srow] =                                            \
                ((float)(racc + (double)brout) > 0.0f) ? 1 : 0;               \
    }

    // ---- prologue staging: tile 0 staged, tile 1 loads left IN FLIGHT ----
    ISSUE(0);
    CONSUME(0);
    ISSUE(1);
    asm volatile("s_waitcnt lgkmcnt(0)" ::: "memory");
    __builtin_amdgcn_s_barrier();

    for (int it = 0; it < iters; ++it) {
        // ---- 1) store tile it-1 (4KB contiguous; ack never waited on) ----
        if (it > 0) {
            const f32x4 ov = *(const f32x4*)
                &obuf[(it - 1) & 1][(tid >> 4) * OTS + (tid & 15) * 4];
            *(f32x4*)(out + ROW0(it - 1) * DIMC + (size_t)tid * 4) = ov;
        }

        // ---- 2) MFMA tile it: 8 K-steps, both children ----
        const __bf16* xb = &xb16[it & 1][0];
        f32x4 accL = {0.f,0.f,0.f,0.f}, accR = {0.f,0.f,0.f,0.f};
        const int axr = m & 7;
#pragma unroll
        for (int s = 0; s < 8; ++s) {
            const int p = s * 4 + g;
            const bf16x8 a = *(const bf16x8*)&xb[m * DIMD + ((p ^ axr) << 3)];
            accL = __builtin_amdgcn_mfma_f32_16x16x32_bf16(a, bL[s], accL, 0, 0, 0);
            accR = __builtin_amdgcn_mfma_f32_16x16x32_bf16(a, bR[s], accR, 0, 0, 0);
        }

        // ---- 3) consume tile it+1 (loads issued LAST iter; counted vmcnt —
        //         the step-1 store is newer, stays in flight) ----
        if (it + 1 < iters) CONSUME(it + 1);

        // ---- 4) issue tile it+2 (loads stay in flight ACROSS the barrier) ----
        if (it + 2 < iters) ISSUE(it + 2);

        // ---- 5) epilogue tile it: select child per row -> obuf[it&1] ----
        const i32x4 mk = *(const i32x4*)&mask_lds[it & 1][g * 4];
#pragma unroll
        for (int r = 0; r < 4; ++r) {
            const float v = mk[r] ? (accL[r] + biasL) : (accR[r] + biasR);
            obuf[it & 1][(g * 4 + r) * OTS + col] = v;   // C/D: row=(lane>>4)*4+reg
        }

        // ---- 6) barrier: lgkm-only; loads(it+2) + store(it-1) in flight ----
        asm volatile("s_waitcnt lgkmcnt(0)" ::: "memory");
        __builtin_amdgcn_s_barrier();
    }

    // ---- drain: store last tile ----
    {
        const int it = iters - 1;
        const f32x4 ov = *(const f32x4*)
            &obuf[it & 1][(tid >> 4) * OTS + (tid & 15) * 4];
        *(f32x4*)(out + ROW0(it) * DIMC + (size_t)tid * 4) = ov;
    }
#undef ISSUE
#undef CONSUME
#undef ROW0
}

extern "C" void kernel_launch(void* const* d_in, const int* in_sizes, int n_in,
                              void* d_out, int out_size, void* d_ws, size_t ws_size,
                              hipStream_t stream) {
    const float* x        = (const float*)d_in[0];
    const float* w_router = (const float*)d_in[1];
    const float* b_router = (const float*)d_in[2];
    const float* w_left   = (const float*)d_in[3];
    const float* b_left   = (const float*)d_in[4];
    const float* w_right  = (const float*)d_in[5];
    const float* b_right  = (const float*)d_in[6];
    float* out = (float*)d_out;

    const int n_tok = in_sizes[0] / DIMD;   // 1,048,576
    const int grid  = 1024;                 // 4 blocks/CU x 256 CU (LDS ~26 KB)
    const int iters = n_tok / (grid * RPT); // 64

    tree_node_kernel<<<grid, 256, 0, stream>>>(
        x, w_router, b_router, w_left, b_left, w_right, b_right, out, iters);
}

// Round 11
// 287.148 us; speedup vs baseline: 1.9767x; 1.0001x over previous
//
#include <hip/hip_runtime.h>
#include <hip/hip_bf16.h>

#define DIMD 256
#define DIMC 64
#define RPT  16   // rows per tile

typedef __attribute__((ext_vector_type(8))) __bf16 bf16x8;
typedef __attribute__((ext_vector_type(4))) __bf16 bf16x4;
typedef __attribute__((ext_vector_type(4))) float f32x4;

__global__ __launch_bounds__(256, 4) void tree_node_kernel(
    const float* __restrict__ x,
    const float* __restrict__ w_router,
    const float* __restrict__ b_router,
    const float* __restrict__ w_left,
    const float* __restrict__ b_left,
    const float* __restrict__ w_right,
    const float* __restrict__ b_right,
    float* __restrict__ out,
    int iters)
{
    __shared__ __bf16 xb16[2][RPT * DIMD];                  // 2 x 8 KB, swizzled
    __shared__ float  wr_s[DIMD];                           // 1 KB router w
    __shared__ int    mask_lds[2][RPT] __attribute__((aligned(16)));

    const int tid  = threadIdx.x;
    const int lane = tid & 63;
    const int wave = tid >> 6;
    const int g    = lane >> 4;   // k-group 0..3 (MFMA)
    const int m    = lane & 15;   // A/B minor index; with swapped operands m = TOKEN row
    const int srow = tid >> 4;    // staging row 0..15
    const int sm   = tid & 15;    // staging chunk 0..15

    // ---- prologue: W fragments -> registers. Same fragments as before, but
    //      they will be the MFMA *A* operand (w^T tile): lane(g,m) holds
    //      w[k=s*32+g*8+j][wave*16+m]. ----
    const int colbase = wave * 16;
    bf16x8 bL[8], bR[8];
#pragma unroll
    for (int s = 0; s < 8; ++s)
#pragma unroll
        for (int j = 0; j < 8; ++j) {
            const int k = s * 32 + g * 8 + j;
            bL[s][j] = (__bf16)w_left[k * DIMC + colbase + m];
            bR[s][j] = (__bf16)w_right[k * DIMC + colbase + m];
        }
    // per-lane biases for this lane's 4 output classes (cols wave*16+g*4+r)
    float biasL4[4], biasR4[4];
#pragma unroll
    for (int r = 0; r < 4; ++r) {
        biasL4[r] = b_left[colbase + g * 4 + r];
        biasR4[r] = b_right[colbase + g * 4 + r];
    }
    const float brout = b_router[0];
    wr_s[tid] = w_router[tid];

    // GRID-STRIDED tile mapping (dense moving front)
    const size_t row_base   = (size_t)blockIdx.x * RPT;
    const size_t row_stride = (size_t)gridDim.x * RPT;
#define ROW0(itile) (row_base + (size_t)(itile) * row_stride)

    __syncthreads();   // wr_s ready

    f32x4 sx[4];       // staged f32 (one 16-float slice of one row)

#define ISSUE(itile)                                                          \
    {                                                                         \
        const float* xr = x + (ROW0(itile) + srow) * DIMD + sm * 4;           \
        _Pragma("unroll")                                                     \
        for (int j = 0; j < 4; ++j) sx[j] = *(const f32x4*)(xr + j * 64);     \
    }

    // consume: fp64 router partial + cvt bf16 + swizzled LDS write + mask.
    // swizzle: 16B piece p -> p ^ (row&7); same involution on B-frag reads.
#define CONSUME(itile)                                                        \
    {                                                                         \
        const int slot = (itile) & 1;                                         \
        double racc = 0.0;                                                    \
        const int rx = srow & 7;                                              \
        _Pragma("unroll")                                                     \
        for (int j = 0; j < 4; ++j) {                                         \
            const f32x4 wv = *(const f32x4*)&wr_s[sm * 4 + j * 64];           \
            bf16x4 v;                                                         \
            _Pragma("unroll")                                                 \
            for (int e = 0; e < 4; ++e) {                                     \
                racc += (double)sx[j][e] * (double)wv[e];                     \
                v[e] = (__bf16)sx[j][e];                                      \
            }                                                                 \
            const int p = (sm >> 1) + 8 * j;                                  \
            *(bf16x4*)&xb16[slot][srow * DIMD +                               \
                (((p ^ rx) << 3) | ((sm & 1) << 2))] = v;                     \
        }                                                                     \
        racc += __shfl_xor(racc, 1);                                          \
        racc += __shfl_xor(racc, 2);                                          \
        racc += __shfl_xor(racc, 4);                                          \
        racc += __shfl_xor(racc, 8);                                          \
        if (sm == 0)                                                          \
            mask_lds[slot][srow] =                                            \
                ((float)(racc + (double)brout) > 0.0f) ? 1 : 0;               \
    }

    // ---- prologue staging: tile 0 staged, tile 1 loads left IN FLIGHT ----
    ISSUE(0);
    CONSUME(0);
    ISSUE(1);
    asm volatile("s_waitcnt lgkmcnt(0)" ::: "memory");
    __builtin_amdgcn_s_barrier();

    for (int it = 0; it < iters; ++it) {
        // ---- 1) MFMA tile it, OPERAND-SWAPPED: D = (w^T-tile)·(x^T-tile).
        //         acc[r] = out[token m][class wave*16+g*4+r]  (out^T layout) ----
        const __bf16* xb = &xb16[it & 1][0];
        const int lm = mask_lds[it & 1][m];      // this lane's token mask (broadcast)
        f32x4 accL = {0.f,0.f,0.f,0.f}, accR = {0.f,0.f,0.f,0.f};
        const int axr = m & 7;
#pragma unroll
        for (int s = 0; s < 8; ++s) {
            const int p = s * 4 + g;
            const bf16x8 a = *(const bf16x8*)&xb[m * DIMD + ((p ^ axr) << 3)];
            accL = __builtin_amdgcn_mfma_f32_16x16x32_bf16(bL[s], a, accL, 0, 0, 0);
            accR = __builtin_amdgcn_mfma_f32_16x16x32_bf16(bR[s], a, accR, 0, 0, 0);
        }

        // ---- 2) select child + bias, store DIRECT from acc: 16B/lane at
        //         out[row0+m][wave*16+g*4]; 4 lanes/row -> 64B chunks, L2-merged ----
        {
            f32x4 ov;
#pragma unroll
            for (int r = 0; r < 4; ++r)
                ov[r] = lm ? (accL[r] + biasL4[r]) : (accR[r] + biasR4[r]);
            *(f32x4*)(out + (ROW0(it) + m) * DIMC + colbase + g * 4) = ov;
        }

        // ---- 3) consume tile it+1 (loads issued LAST iter; counted vmcnt —
        //         the step-2 store is newer in the FIFO, stays in flight) ----
        if (it + 1 < iters) CONSUME(it + 1);

        // ---- 4) issue tile it+2 (loads stay in flight ACROSS the barrier) ----
        if (it + 2 < iters) ISSUE(it + 2);

        // ---- 5) barrier: lgkm-only (publishes xb16[it+1] + mask).
        //         NO vmcnt drain: loads(it+2) + store(it) stay in flight ----
        asm volatile("s_waitcnt lgkmcnt(0)" ::: "memory");
        __builtin_amdgcn_s_barrier();
    }
#undef ISSUE
#undef CONSUME
#undef ROW0
}

extern "C" void kernel_launch(void* const* d_in, const int* in_sizes, int n_in,
                              void* d_out, int out_size, void* d_ws, size_t ws_size,
                              hipStream_t stream) {
    const float* x        = (const float*)d_in[0];
    const float* w_router = (const float*)d_in[1];
    const float* b_router = (const float*)d_in[2];
    const float* w_left   = (const float*)d_in[3];
    const float* b_left   = (const float*)d_in[4];
    const float* w_right  = (const float*)d_in[5];
    const float* b_right  = (const float*)d_in[6];
    float* out = (float*)d_out;

    const int n_tok = in_sizes[0] / DIMD;   // 1,048,576
    const int grid  = 1024;                 // 4 blocks/CU x 256 CU (LDS ~18 KB)
    const int iters = n_tok / (grid * RPT); // 64

    tree_node_kernel<<<grid, 256, 0, stream>>>(
        x, w_router, b_router, w_left, b_left, w_right, b_right, out, iters);
}